// Round 1
// baseline (135.419 us; speedup 1.0000x reference)
//
#include <hip/hip_runtime.h>

typedef _Float16 f16;
typedef unsigned short u16;
typedef __attribute__((ext_vector_type(8))) f16 f16x8;
typedef __attribute__((ext_vector_type(4))) f16 f16x4;
typedef __attribute__((ext_vector_type(4))) float floatx4;

#define NPIX 4096
#define KT   128          // keys per attention tile
#define NT   (NPIX / KT)  // 32 key tiles
#define KROW 40           // padded K LDS row (32 d + 8) in f16 -> conflict-free b128 reads
#define VROW 136          // padded V LDS row (128 keys + 8) in f16

// ---------------------------------------------------------------------------
// Kernel 1: QKV projection as fp16 MFMA GEMM.  (unchanged)
// grid (64 p-tiles, 6 o-tiles of 64, 4 b), block 256 (4 waves).
// ---------------------------------------------------------------------------
__global__ __launch_bounds__(256) void qkv_mfma(
    const float* __restrict__ x, const float* __restrict__ w,
    f16* __restrict__ qh, f16* __restrict__ kh, f16* __restrict__ vth)
{
    __shared__ f16 wlds[64 * 136];     // [o][c] padded (+8) -> conflict-free frags
    const int tid  = threadIdx.x;
    const int wave = tid >> 6;
    const int lane = tid & 63;
    const int quad = lane >> 4;
    const int l16  = lane & 15;
    const int pbase = blockIdx.x * 64;
    const int y     = blockIdx.y;      // o-tile of 64; type = y>>1
    const int b     = blockIdx.z;

#pragma unroll
    for (int i = 0; i < 8; ++i) {
        int idx = i * 256 + tid;               // 2048 float4
        int o = idx >> 5, ch = idx & 31;
        float4 wv = *(const float4*)(w + (size_t)(y * 64 + o) * 128 + ch * 4);
        f16x4 h; h[0] = (f16)wv.x; h[1] = (f16)wv.y; h[2] = (f16)wv.z; h[3] = (f16)wv.w;
        *(f16x4*)&wlds[o * 136 + ch * 4] = h;
    }
    __syncthreads();

    const float* xb = x + (size_t)b * 128 * NPIX;
    const int type = y >> 1;                   // 0=q 1=k 2=v

    if (type < 2) {
        // ---- C[p][o]: A = X^T (global), B = W (LDS) ----
        const int p_row = pbase + wave * 16 + l16;
        f16x8 af[4];
#pragma unroll
        for (int kc = 0; kc < 4; ++kc) {
            const int c0 = kc * 32 + quad * 8;
#pragma unroll
            for (int j = 0; j < 8; ++j)
                af[kc][j] = (f16)xb[(size_t)(c0 + j) * NPIX + p_row];
        }
        floatx4 acc[4];
#pragma unroll
        for (int n = 0; n < 4; ++n) acc[n] = floatx4{0.f, 0.f, 0.f, 0.f};
#pragma unroll
        for (int n = 0; n < 4; ++n)
#pragma unroll
            for (int kc = 0; kc < 4; ++kc) {
                f16x8 bf = *(const f16x8*)&wlds[(n * 16 + l16) * 136 + kc * 32 + quad * 8];
                acc[n] = __builtin_amdgcn_mfma_f32_16x16x32_f16(af[kc], bf, acc[n], 0, 0, 0);
            }
        const float qs = (type == 0) ? 0.17677669529663687f * 1.4426950408889634f : 1.0f;
        f16* dst = (type == 0) ? qh : kh;
#pragma unroll
        for (int n = 0; n < 4; ++n) {
            const int og   = y * 64 + n * 16 + l16;
            const int head = (og >> 5) & 3;
            const int d    = og & 31;
            f16* base = dst + (size_t)(b * 4 + head) * NPIX * 32;
#pragma unroll
            for (int r = 0; r < 4; ++r) {
                const int p = pbase + wave * 16 + quad * 4 + r;
                base[(size_t)p * 32 + d] = (f16)(acc[n][r] * qs);
            }
        }
    } else {
        // ---- C[o][p]: A = W (LDS), B = X (global) ----
        const int p_col = pbase + wave * 16 + l16;
        f16x8 bf[4];
#pragma unroll
        for (int kc = 0; kc < 4; ++kc) {
            const int c0 = kc * 32 + quad * 8;
#pragma unroll
            for (int j = 0; j < 8; ++j)
                bf[kc][j] = (f16)xb[(size_t)(c0 + j) * NPIX + p_col];
        }
        floatx4 acc[4];
#pragma unroll
        for (int m = 0; m < 4; ++m) acc[m] = floatx4{0.f, 0.f, 0.f, 0.f};
#pragma unroll
        for (int m = 0; m < 4; ++m)
#pragma unroll
            for (int kc = 0; kc < 4; ++kc) {
                f16x8 af = *(const f16x8*)&wlds[(m * 16 + l16) * 136 + kc * 32 + quad * 8];
                acc[m] = __builtin_amdgcn_mfma_f32_16x16x32_f16(af, bf[kc], acc[m], 0, 0, 0);
            }
#pragma unroll
        for (int m = 0; m < 4; ++m)
#pragma unroll
            for (int r = 0; r < 4; ++r) {
                const int og   = y * 64 + m * 16 + quad * 4 + r;
                const int head = (og >> 5) & 3;
                const int d    = og & 31;
                vth[((size_t)(b * 4 + head) * 32 + d) * NPIX + p_col] = (f16)acc[m][r];
            }
    }
}

// ---------------------------------------------------------------------------
// Kernel 2: flash attention via S^T = K*Q^T.
// v2 changes vs. baseline:
//  - klds rows padded to 40 f16 (80 B): l16-group bank starts 20*l16 mod 32 are
//    all distinct -> kills the 8-way conflict on the 8 kf ds_read_b128 / kt
//    (was 7.34M SQ_LDS_BANK_CONFLICT cycles = 112 cyc/wave/kt).
//  - double-buffered K & V (37.9 KB LDS): ONE barrier per kt; next tile's
//    global loads issued BEFORE compute so HBM/L2 latency hides under MFMA+exp.
//  - lsum via ones-column MFMA (B=1): moves 64 v_add_f32/wave/kt off the VALU
//    onto the MFMA pipe AND lands the denominator on the storing lane
//    (D row = quad*4+r == oacc row) -> shuffle-free epilogue.
//  - s_setprio(1) around MFMA clusters (measured +4-7% on attention).
// grid (32 q-blocks of 128, 16 bh), block 256 (4 waves x 32 q).
// ---------------------------------------------------------------------------
__global__ __launch_bounds__(256, 2) void attn_kernel(
    const f16* __restrict__ qh, const f16* __restrict__ kh,
    const f16* __restrict__ vth, f16* __restrict__ att)
{
    __shared__ f16 klds[2][KT * KROW];   // 2 x 10.0 KB, padded [key][d]
    __shared__ f16 vlds[2][32 * VROW];   // 2 x 8.5 KB, padded [d][key]

    const int tid  = threadIdx.x;
    const int wave = tid >> 6;
    const int lane = tid & 63;
    const int quad = lane >> 4;
    const int l16  = lane & 15;
    const int bh   = blockIdx.y;
    const int qbase = blockIdx.x * 128 + wave * 32;

    const f16* kb = kh + (size_t)bh * NPIX * 32;
    const f16* vb = vth + (size_t)bh * 32 * NPIX;

    // staging geometry: 256 threads, K tile = 512 int4 (2/thread), V tile = 512 int4
    const int kr0 = tid >> 2, kc4 = tid & 3;        // K rows 0..63   (idx = tid)
    const int kr1 = (tid + 256) >> 2;               // K rows 64..127 (idx = tid+256)
    const int koff0 = kr0 * KROW + kc4 * 8;
    const int koff1 = kr1 * KROW + kc4 * 8;
    const int vr = tid >> 3, vc = (tid & 7) * 2;    // V: 32 rows x 16 int4
    const int voff = vr * VROW + vc * 8;

    // Q B-frags (B[k=d][n=q]): two 16-q subtiles
    f16x8 qB[2];
#pragma unroll
    for (int h = 0; h < 2; ++h)
        qB[h] = *(const f16x8*)(qh + ((size_t)bh * NPIX + qbase + h * 16 + l16) * 32 + quad * 8);

    floatx4 oacc[2][2];
    floatx4 lacc[2];
#pragma unroll
    for (int h = 0; h < 2; ++h) {
        lacc[h] = floatx4{0.f, 0.f, 0.f, 0.f};
#pragma unroll
        for (int dh = 0; dh < 2; ++dh) oacc[h][dh] = floatx4{0.f, 0.f, 0.f, 0.f};
    }
    const f16x4 vones = {(f16)1.f, (f16)1.f, (f16)1.f, (f16)1.f};

    // prologue: stage tile 0 into buffer 0
    {
        const int4* ks = (const int4*)kb;
        int4 k0 = ks[tid], k1 = ks[tid + 256];
        const int4* vs = (const int4*)(vb + (size_t)vr * NPIX);
        int4 v0 = vs[vc], v1 = vs[vc + 1];
        *(int4*)&klds[0][koff0] = k0;
        *(int4*)&klds[0][koff1] = k1;
        *(int4*)&vlds[0][voff]     = v0;
        *(int4*)&vlds[0][voff + 8] = v1;
    }
    __syncthreads();

    for (int kt = 0; kt < NT; ++kt) {
        const int cur = kt & 1;
        const bool more = (kt + 1 < NT);

        // issue next tile's global loads FIRST: latency hides under compute
        int4 k0, k1, v0, v1;
        if (more) {
            const int4* ks = (const int4*)(kb + (size_t)(kt + 1) * KT * 32);
            k0 = ks[tid]; k1 = ks[tid + 256];
            const int4* vs = (const int4*)(vb + (size_t)vr * NPIX + (kt + 1) * KT);
            v0 = vs[vc]; v1 = vs[vc + 1];
        }

        // register-cache K A-frags (A[m=key][k=d]) and V B-frags (B[k=key][n=d])
        f16x8 kf[8];
#pragma unroll
        for (int t = 0; t < 8; ++t)
            kf[t] = *(const f16x8*)&klds[cur][(t * 16 + l16) * KROW + quad * 8];
        f16x4 vf[8][2];
#pragma unroll
        for (int c = 0; c < 8; ++c)
#pragma unroll
            for (int dh = 0; dh < 2; ++dh)
                vf[c][dh] = *(const f16x4*)&vlds[cur][(dh * 16 + l16) * VROW + c * 16 + quad * 4];

#pragma unroll
        for (int h = 0; h < 2; ++h) {
            // S^T: D[key][q], 8 subtiles of 16 keys, full K=32 reduction
            floatx4 st[8];
            __builtin_amdgcn_s_setprio(1);
#pragma unroll
            for (int t = 0; t < 8; ++t) {
                floatx4 z = {0.f, 0.f, 0.f, 0.f};
                st[t] = __builtin_amdgcn_mfma_f32_16x16x32_f16(kf[t], qB[h], z, 0, 0, 0);
            }
            __builtin_amdgcn_s_setprio(0);
            // exp2 in-lane -> P A-frags (P[q=l16][key=quad*4+r])
            f16x4 pf[8];
#pragma unroll
            for (int c = 0; c < 8; ++c)
#pragma unroll
                for (int r = 0; r < 4; ++r)
                    pf[c][r] = (f16)__builtin_amdgcn_exp2f(st[c][r]);
            // PV: O[q][d] += P[q][key]*V[key][d]; ones-column MFMA accumulates
            // the softmax denominator exactly (f32) on the MFMA pipe.
            __builtin_amdgcn_s_setprio(1);
#pragma unroll
            for (int c = 0; c < 8; ++c) {
                oacc[h][0] = __builtin_amdgcn_mfma_f32_16x16x16f16(pf[c], vf[c][0], oacc[h][0], 0, 0, 0);
                oacc[h][1] = __builtin_amdgcn_mfma_f32_16x16x16f16(pf[c], vf[c][1], oacc[h][1], 0, 0, 0);
                lacc[h]    = __builtin_amdgcn_mfma_f32_16x16x16f16(pf[c], vones,    lacc[h],    0, 0, 0);
            }
            __builtin_amdgcn_s_setprio(0);
        }

        // publish next tile (writes wait on vmcnt here, after compute)
        if (more) {
            const int nb = cur ^ 1;
            *(int4*)&klds[nb][koff0] = k0;
            *(int4*)&klds[nb][koff1] = k1;
            *(int4*)&vlds[nb][voff]     = v0;
            *(int4*)&vlds[nb][voff + 8] = v1;
        }
        __syncthreads();
    }

    // epilogue: lacc[h][r] is the denom for q = quad*4+r — same lane as oacc rows.
#pragma unroll
    for (int h = 0; h < 2; ++h)
#pragma unroll
        for (int r = 0; r < 4; ++r) {
            const float inv = 1.0f / lacc[h][r];
            const int q = qbase + h * 16 + quad * 4 + r;
            f16* ob = att + ((size_t)bh * NPIX + q) * 32;
            ob[l16]      = (f16)(oacc[h][0][r] * inv);
            ob[16 + l16] = (f16)(oacc[h][1][r] * inv);
        }
}

// ---------------------------------------------------------------------------
// Kernel 3: output projection as fp16 MFMA GEMM.
// v2: o-dimension split across blockIdx.y (2 halves of 64) -> 512 blocks
// (2/CU instead of 1/CU), half the W staging per block.
// grid (64 p-tiles, 2 o-halves, 4 b), block 256 (4 waves).
// ---------------------------------------------------------------------------
__global__ __launch_bounds__(256) void proj_mfma(
    const f16* __restrict__ att, const float* __restrict__ wp,
    const float* __restrict__ bp, float* __restrict__ out)
{
    __shared__ f16 wplds[64 * 136];    // [o][c] padded, 17.4 KB
    __shared__ float bplds[64];
    const int tid  = threadIdx.x;
    const int wave = tid >> 6;
    const int lane = tid & 63;
    const int quad = lane >> 4;
    const int l16  = lane & 15;
    const int pbase = blockIdx.x * 64;
    const int oh    = blockIdx.y;      // o-half: rows oh*64 .. oh*64+63
    const int b     = blockIdx.z;

    if (tid < 64) bplds[tid] = bp[oh * 64 + tid];
#pragma unroll
    for (int i = 0; i < 8; ++i) {
        int idx = i * 256 + tid;               // 2048 float4 = 64*128 floats
        int o = idx >> 5, ch = idx & 31;
        float4 wv = *(const float4*)(wp + (size_t)(oh * 64 + o) * 128 + ch * 4);
        f16x4 h; h[0] = (f16)wv.x; h[1] = (f16)wv.y; h[2] = (f16)wv.z; h[3] = (f16)wv.w;
        *(f16x4*)&wplds[o * 136 + ch * 4] = h;
    }
    __syncthreads();

    const f16* ab = att + (size_t)b * 4 * NPIX * 32;
    const int p_col = pbase + wave * 16 + l16;
    f16x8 bf[4];
#pragma unroll
    for (int kc = 0; kc < 4; ++kc)
        bf[kc] = *(const f16x8*)(ab + ((size_t)kc * NPIX + p_col) * 32 + quad * 8);

    floatx4 acc[4];
#pragma unroll
    for (int m = 0; m < 4; ++m) acc[m] = floatx4{0.f, 0.f, 0.f, 0.f};
#pragma unroll
    for (int m = 0; m < 4; ++m)
#pragma unroll
        for (int kc = 0; kc < 4; ++kc) {
            f16x8 af = *(const f16x8*)&wplds[(m * 16 + l16) * 136 + kc * 32 + quad * 8];
            acc[m] = __builtin_amdgcn_mfma_f32_16x16x32_f16(af, bf[kc], acc[m], 0, 0, 0);
        }

#pragma unroll
    for (int m = 0; m < 4; ++m)
#pragma unroll
        for (int r = 0; r < 4; ++r) {
            const int o = m * 16 + quad * 4 + r;
            out[((size_t)b * 128 + oh * 64 + o) * NPIX + p_col] = acc[m][r] + bplds[o];
        }
}

// ---------------------------------------------------------------------------
extern "C" void kernel_launch(void* const* d_in, const int* in_sizes, int n_in,
                              void* d_out, int out_size, void* d_ws, size_t ws_size,
                              hipStream_t stream)
{
    const float* x      = (const float*)d_in[0];
    const float* w_qkv  = (const float*)d_in[1];
    const float* w_proj = (const float*)d_in[2];
    const float* b_proj = (const float*)d_in[3];
    float* out = (float*)d_out;

    char* ws = (char*)d_ws;
    f16* qh  = (f16*)(ws);                // 16*4096*32 f16 = 4 MB, pre-scaled
    f16* kh  = (f16*)(ws + (4u << 20));   // 4 MB [bh][p][32]
    f16* vth = (f16*)(ws + (8u << 20));   // 4 MB [bh][d][p]
    f16* att = (f16*)(ws + (12u << 20));  // 4 MB [bh][p][32]

    qkv_mfma<<<dim3(64, 6, 4), 256, 0, stream>>>(x, w_qkv, qh, kh, vth);
    attn_kernel<<<dim3(32, 16, 1), 256, 0, stream>>>(qh, kh, vth, att);
    proj_mfma<<<dim3(64, 2, 4), 256, 0, stream>>>(att, w_proj, b_proj, out);
}